// Round 17
// baseline (759.404 us; speedup 1.0000x reference)
//
#include <hip/hip_runtime.h>
#include <math.h>

#define NN 50000
#define NE 1600000
#define H  64

#define SHIFT 7                 // 128 nodes per bucket
#define NPBKT 128
#define NB    391               // ceil(50000/128)
#define CHUNK 4096
#define NCH   391               // ceil(NE/CHUNK)
#define NBLK  ((NN + 63) / 64)  // 782 fused blocks (64-node strips)

typedef __attribute__((ext_vector_type(8))) short s16v8;   // 8 bf16
typedef __attribute__((ext_vector_type(4))) float f32v4;   // MFMA acc
typedef __attribute__((ext_vector_type(8))) _Float16 f16v8;
typedef unsigned short u16;
typedef unsigned int   u32;

__device__ __forceinline__ u16 f2bf(float x) {             // RNE f32->bf16
    union { float f; unsigned u; } v; v.f = x;
    unsigned r = v.u + 0x7FFF + ((v.u >> 16) & 1);
    return (u16)(r >> 16);
}
__device__ __forceinline__ float bf2f(u16 h) {
    union { float f; unsigned u; } v; v.u = ((unsigned)h) << 16; return v.f;
}

// ============ CSR build, bucketized ============
__global__ __launch_bounds__(256) void hist_kernel(const int* __restrict__ dst,
                                                   int* __restrict__ chunkhist) {
    __shared__ int h[NB];
    const int c = blockIdx.x;
    for (int b = threadIdx.x; b < NB; b += 256) h[b] = 0;
    __syncthreads();
    const int e0 = c * CHUNK, e1 = min(NE, e0 + CHUNK);
    for (int e = e0 + threadIdx.x; e < e1; e += 256)
        atomicAdd(&h[dst[e] >> SHIFT], 1);
    __syncthreads();
    for (int b = threadIdx.x; b < NB; b += 256)
        chunkhist[c * NB + b] = h[b];
}

__global__ __launch_bounds__(512) void cscan_kernel(int* __restrict__ chunkhist,
                                                    int* __restrict__ bbase) {
    __shared__ int s[512];
    const int t = threadIdx.x;
    int tot = 0;
    if (t < NB)
        for (int c = 0; c < NCH; ++c) tot += chunkhist[c * NB + t];
    s[t] = (t < NB) ? tot : 0;
    __syncthreads();
    for (int d = 1; d < 512; d <<= 1) {
        int v = (t >= d) ? s[t - d] : 0;
        __syncthreads();
        s[t] += v;
        __syncthreads();
    }
    if (t < NB) {
        int base = s[t] - tot;             // exclusive
        bbase[t] = base;
        if (t == NB - 1) bbase[NB] = s[t];
        int run = base;
        for (int c = 0; c < NCH; ++c) {
            int tmp = chunkhist[c * NB + t];
            chunkhist[c * NB + t] = run;
            run += tmp;
        }
    }
}

__global__ __launch_bounds__(256) void scat_kernel(const int* __restrict__ src,
                                                   const int* __restrict__ dst,
                                                   const int* __restrict__ chunkhist,
                                                   u32* __restrict__ bin) {
    __shared__ int base[NB];
    __shared__ int cur[NB];
    const int c = blockIdx.x;
    for (int b = threadIdx.x; b < NB; b += 256) {
        base[b] = chunkhist[c * NB + b];
        cur[b] = 0;
    }
    __syncthreads();
    const int e0 = c * CHUNK, e1 = min(NE, e0 + CHUNK);
    for (int e = e0 + threadIdx.x; e < e1; e += 256) {
        int d = dst[e];
        int b = d >> SHIFT;
        int p = atomicAdd(&cur[b], 1);
        bin[base[b] + p] = (u32)src[e] | ((u32)(d & (NPBKT - 1)) << 16);
    }
}

// per-bucket: degrees -> local scan -> off[] and u32 csr2 (src | local<<16)
__global__ __launch_bounds__(256) void binB_kernel(const u32* __restrict__ bin,
                                                   const int* __restrict__ bbase,
                                                   int* __restrict__ off,
                                                   u32* __restrict__ csr2) {
    __shared__ int deg[NPBKT];
    __shared__ int sc[NPBKT];
    __shared__ int cur[NPBKT];
    const int b = blockIdx.x, t = threadIdx.x;
    const int seg0 = bbase[b], seg1 = bbase[b + 1];
    if (t < NPBKT) { deg[t] = 0; cur[t] = 0; }
    __syncthreads();
    for (int i = seg0 + t; i < seg1; i += 256)
        atomicAdd(&deg[(bin[i] >> 16) & (NPBKT - 1)], 1);
    __syncthreads();
    if (t < NPBKT) sc[t] = deg[t];
    __syncthreads();
    for (int d = 1; d < NPBKT; d <<= 1) {
        int v = 0;
        if (t < NPBKT && t >= d) v = sc[t - d];
        __syncthreads();
        if (t < NPBKT) sc[t] += v;
        __syncthreads();
    }
    if (t < NPBKT) {
        sc[t] -= deg[t];
        int node = b * NPBKT + t;
        if (node < NN) off[node] = seg0 + sc[t];
        if (b == 0 && t == 0) off[NN] = NE;
    }
    __syncthreads();
    for (int i = seg0 + t; i < seg1; i += 256) {
        u32 e = bin[i];
        int n = (e >> 16) & (NPBKT - 1);
        int p = atomicAdd(&cur[n], 1);
        csr2[seg0 + sc[n] + p] = (e & 0xFFFF) | ((u32)n << 16);
    }
}

// ============ weight prep: transpose + split into bf16 hi/lo planes ======
__global__ __launch_bounds__(256) void prep_kernel(const float* __restrict__ W1,
        const float* __restrict__ W2, const float* __restrict__ W3,
        u16* __restrict__ wt) {
    int idx = blockIdx.x * 256 + threadIdx.x;
    if (idx >= 2 * 40960) return;
    int b = idx / 40960, r = idx - b * 40960;
    float v; int hioff, losz;
    if (r < 16384) {
        int col = r >> 7, k = r & 127;
        v = W1[b * 24576 + k * 128 + col];
        hioff = b * 81920 + r; losz = 16384;
    } else if (r < 32768) {
        int rr = r - 16384; int col = rr >> 7, k = rr & 127;
        v = W2[b * 16384 + k * 128 + col];
        hioff = b * 81920 + 32768 + rr; losz = 16384;
    } else {
        int rr = r - 32768; int col = rr >> 7, k = rr & 127;
        v = W3[b * 8192 + k * 64 + col];
        hioff = b * 81920 + 65536 + rr; losz = 8192;
    }
    u16 hi = f2bf(v);
    u16 lo = f2bf(v - bf2f(hi));
    wt[hioff] = hi; wt[hioff + losz] = lo;
}

// ============ grep partials + fp16 copy (it=0 only) ============
__global__ __launch_bounds__(256) void grep_kernel(const float* __restrict__ h,
                                                   float* __restrict__ partial,
                                                   _Float16* __restrict__ h16) {
    const int c  = threadIdx.x & 63;
    const int rl = threadIdx.x >> 6;
    float acc = 0.f;
    for (int r = blockIdx.x * 4 + rl; r < NN; r += gridDim.x * 4) {
        float v = h[r * H + c];
        h16[r * H + c] = (_Float16)v;
        acc += v;
    }
    __shared__ float s[4][64];
    s[rl][c] = acc;
    __syncthreads();
    if (threadIdx.x < 64)
        partial[blockIdx.x * 64 + threadIdx.x] =
            s[0][threadIdx.x] + s[1][threadIdx.x] +
            s[2][threadIdx.x] + s[3][threadIdx.x];
}

// ============ b1e: 1024-thread reduce + fold grep into layer-1 bias ======
__global__ __launch_bounds__(1024) void b1e_kernel(const float* __restrict__ partial,
        int nparts,
        const float* __restrict__ W1, const float* __restrict__ b1,
        float* __restrict__ b1e) {
    __shared__ float sg[16][64];
    __shared__ float g[64];
    const int t = threadIdx.x;
    const int c = t & 63, rl = t >> 6;           // rl in [0,16)
    float s = 0.f;
    for (int i = rl; i < nparts; i += 16) s += partial[i * 64 + c];
    sg[rl][c] = s;
    __syncthreads();
    if (t < 64) {
        float a = 0.f;
#pragma unroll
        for (int j = 0; j < 16; ++j) a += sg[j][t];
        g[t] = a;
    }
    __syncthreads();
    if (t < 128) {
        float s2 = b1[t];
        for (int k = 0; k < 64; ++k)
            s2 = fmaf(g[k], W1[(128 + k) * 128 + t], s2);
        b1e[t] = s2;
    }
}

// ============ FUSED balanced-gather + MFMA MLP (R12 body) ============
// 64 nodes/block, 8 waves. Gather: strip's edges are CONTIGUOUS in csr2;
// each 8-lane oct takes an equal slice (4 subchains), register-accumulates
// same-node runs, flushes via LDS atomicAdd only at node boundaries.
// fp32 accumulator aliases the hlo plane (LDS stays ~33 KB).
#define MLP_MFMA(d, a, b) d = __builtin_amdgcn_mfma_f32_16x16x32_bf16(a, b, d, 0, 0, 0)

__global__ __launch_bounds__(512, 4) void fused_mlp(
    const _Float16* __restrict__ h16in, const float* __restrict__ hin,
    const float* __restrict__ b1e, const u16* __restrict__ wt,
    const float* __restrict__ b2, const float* __restrict__ b3,
    const u32* __restrict__ csr2, const int* __restrict__ off,
    float* __restrict__ out, _Float16* __restrict__ h16out,
    float* __restrict__ colpart)
{
    __shared__ u16 hhi[64 * 128], hlo[64 * 128];
    __shared__ float ssw[4][64];
    __shared__ float colp[64];
    const int t = threadIdx.x;
    const int wl = t >> 6, lane = t & 63;
    const int li = lane & 15, g = lane >> 4;
    const int n0 = blockIdx.x * 64;

    const u16* w1hi = wt;
    const u16* w1lo = wt + 16384;
    const u16* w2hi = wt + 32768;
    const u16* w2lo = wt + 49152;
    const u16* w3hi = wt + 65536;
    const u16* w3lo = wt + 73728;

    float* xaccf = (float*)hlo;               // 64*64 f32 = 16 KB (aliases hlo)

    // ---- zero xacc; issue hin loads early ----
#pragma unroll
    for (int i = 0; i < 8; ++i) xaccf[i * 512 + t] = 0.f;
    const int row_t = t >> 3, g8 = t & 7;
    const int hnode = min(n0 + row_t, NN - 1);
    float4 u0 = *(const float4*)(hin + (size_t)hnode * 64 + g8 * 8);
    float4 u1 = *(const float4*)(hin + (size_t)hnode * 64 + g8 * 8 + 4);
    __syncthreads();                          // xacc zeroed

    // ---- balanced gather over the strip's contiguous edge range ----
    {
        const int E0 = off[n0];
        const int E1 = off[min(n0 + 64, NN)];
        const int E  = E1 - E0;
        const int oct = t >> 3;               // 0..63
        const int stripoff = n0 & 127;        // 0 or 64 within bucket
        const int per = (E + 255) >> 8;       // edges per subchain (256 chains)
        int curn[4];
        float a[4][8];
#pragma unroll
        for (int c = 0; c < 4; ++c) {
            curn[c] = -1;
#pragma unroll
            for (int j = 0; j < 8; ++j) a[c][j] = 0.f;
        }
        for (int k = 0; k < per; ++k) {
#pragma unroll
            for (int c = 0; c < 4; ++c) {
                const int cb = E0 + (oct * 4 + c) * per;
                const int e = cb + k;
                if (e < min(cb + per, E1)) {
                    const u32 p = csr2[e];
                    const int d = (int)(p >> 16) - stripoff;
                    if (d != curn[c]) {
                        if (curn[c] >= 0) {
#pragma unroll
                            for (int j = 0; j < 8; ++j)
                                atomicAdd(&xaccf[curn[c] * 64 + g8 * 8 + j], a[c][j]);
                        }
                        curn[c] = d;
#pragma unroll
                        for (int j = 0; j < 8; ++j) a[c][j] = 0.f;
                    }
                    f16v8 v = *(const f16v8*)&h16in[(size_t)(p & 0xFFFFu) * 64 + g8 * 8];
#pragma unroll
                    for (int j = 0; j < 8; ++j) a[c][j] += (float)v[j];
                }
            }
        }
#pragma unroll
        for (int c = 0; c < 4; ++c) {
            if (curn[c] >= 0) {
#pragma unroll
                for (int j = 0; j < 8; ++j)
                    atomicAdd(&xaccf[curn[c] * 64 + g8 * 8 + j], a[c][j]);
            }
        }
    }
    __syncthreads();                          // xacc complete

    // ---- read xacc to regs (before hlo is overwritten) ----
    float xa[8];
    {
        const int base = row_t * 64 + g8 * 8;
#pragma unroll
        for (int j = 0; j < 8; ++j) xa[j] = xaccf[base + j];
    }
    __syncthreads();                          // all xacc reads done

    // ---- write x planes: gather half (cols 0-63) + hin half (64-127) ----
    {
        s16v8 hv, lv;
#pragma unroll
        for (int j = 0; j < 8; ++j) {
            u16 hb = f2bf(xa[j]);
            hv[j] = (short)hb;
            lv[j] = (short)f2bf(xa[j] - bf2f(hb));
        }
        const int addr = row_t * 128 + ((g8 ^ (row_t & 7)) << 3);
        *(s16v8*)&hhi[addr] = hv;
        *(s16v8*)&hlo[addr] = lv;
        float f[8] = {u0.x, u0.y, u0.z, u0.w, u1.x, u1.y, u1.z, u1.w};
        s16v8 hv2, lv2;
#pragma unroll
        for (int j = 0; j < 8; ++j) {
            u16 hb = f2bf(f[j]);
            hv2[j] = (short)hb;
            lv2[j] = (short)f2bf(f[j] - bf2f(hb));
        }
        const int cb2 = 8 + g8;
        const int addr2 = row_t * 128 + ((cb2 ^ (row_t & 7)) << 3);
        *(s16v8*)&hhi[addr2] = hv2;
        *(s16v8*)&hlo[addr2] = lv2;
    }
    __syncthreads();                                   // x ready

    // ================= L1 (x -> h1) =================
    {
        const int col = wl * 16 + li;
        s16v8 Bh[4], Bl[4];
#pragma unroll
        for (int ks = 0; ks < 4; ++ks) {
            Bh[ks] = *(const s16v8*)(w1hi + col * 128 + ks * 32 + g * 8);
            Bl[ks] = *(const s16v8*)(w1lo + col * 128 + ks * 32 + g * 8);
        }
        f32v4 acc[4];
#pragma unroll
        for (int i = 0; i < 4; ++i) acc[i] = (f32v4){0.f, 0.f, 0.f, 0.f};
#pragma unroll
        for (int rt = 0; rt < 4; ++rt) {
            const int row = rt * 16 + li;
#pragma unroll
            for (int ks = 0; ks < 4; ++ks) {
                const int kb = ks * 4 + g;
                const int addr = row * 128 + ((kb ^ (row & 7)) << 3);
                s16v8 Ah = *(const s16v8*)&hhi[addr];
                s16v8 Al = *(const s16v8*)&hlo[addr];
                MLP_MFMA(acc[rt], Ah, Bh[ks]);
                MLP_MFMA(acc[rt], Ah, Bl[ks]);
                MLP_MFMA(acc[rt], Al, Bh[ks]);
            }
        }
        __syncthreads();                        // all x reads complete
        const float bb = b1e[col];
        const int cb = col >> 3, c7 = col & 7;
#pragma unroll
        for (int rt = 0; rt < 4; ++rt) {
#pragma unroll
            for (int r = 0; r < 4; ++r) {
                float hv = fmaxf(acc[rt][r] + bb, 0.f);
                u16 hb = f2bf(hv);
                u16 lb = f2bf(hv - bf2f(hb));
                const int row = rt * 16 + g * 4 + r;
                const int addr = row * 128 + (((cb ^ (row & 7)) << 3) | c7);
                hhi[addr] = hb; hlo[addr] = lb;
            }
        }
    }
    __syncthreads();                                   // h1 ready

    // ================= L2 (h1 -> h2) =================
    {
        const int col = wl * 16 + li;
        s16v8 Bh[4], Bl[4];
#pragma unroll
        for (int ks = 0; ks < 4; ++ks) {
            Bh[ks] = *(const s16v8*)(w2hi + col * 128 + ks * 32 + g * 8);
            Bl[ks] = *(const s16v8*)(w2lo + col * 128 + ks * 32 + g * 8);
        }
        f32v4 acc[4];
#pragma unroll
        for (int i = 0; i < 4; ++i) acc[i] = (f32v4){0.f, 0.f, 0.f, 0.f};
#pragma unroll
        for (int rt = 0; rt < 4; ++rt) {
            const int row = rt * 16 + li;
#pragma unroll
            for (int ks = 0; ks < 4; ++ks) {
                const int kb = ks * 4 + g;
                const int addr = row * 128 + ((kb ^ (row & 7)) << 3);
                s16v8 Ah = *(const s16v8*)&hhi[addr];
                s16v8 Al = *(const s16v8*)&hlo[addr];
                MLP_MFMA(acc[rt], Ah, Bh[ks]);
                MLP_MFMA(acc[rt], Ah, Bl[ks]);
                MLP_MFMA(acc[rt], Al, Bh[ks]);
            }
        }
        __syncthreads();                        // all h1 reads complete
        const float bb = b2[col];
        const int cb = col >> 3, c7 = col & 7;
#pragma unroll
        for (int rt = 0; rt < 4; ++rt) {
#pragma unroll
            for (int r = 0; r < 4; ++r) {
                float hv = fmaxf(acc[rt][r] + bb, 0.f);
                u16 hb = f2bf(hv);
                u16 lb = f2bf(hv - bf2f(hb));
                const int row = rt * 16 + g * 4 + r;
                const int addr = row * 128 + (((cb ^ (row & 7)) << 3) | c7);
                hhi[addr] = hb; hlo[addr] = lb;
            }
        }
    }
    __syncthreads();                                   // h2 ready

    // ========== L3 (h2 -> out, waves 0-3) + norm + h16 + colsum ==========
    float v[4][4];
    if (wl < 4) {
        const int col = wl * 16 + li;
        s16v8 Bh[4], Bl[4];
#pragma unroll
        for (int ks = 0; ks < 4; ++ks) {
            Bh[ks] = *(const s16v8*)(w3hi + col * 128 + ks * 32 + g * 8);
            Bl[ks] = *(const s16v8*)(w3lo + col * 128 + ks * 32 + g * 8);
        }
        f32v4 acc[4];
#pragma unroll
        for (int i = 0; i < 4; ++i) acc[i] = (f32v4){0.f, 0.f, 0.f, 0.f};
#pragma unroll
        for (int rt = 0; rt < 4; ++rt) {
            const int row = rt * 16 + li;
#pragma unroll
            for (int ks = 0; ks < 4; ++ks) {
                const int kb = ks * 4 + g;
                const int addr = row * 128 + ((kb ^ (row & 7)) << 3);
                s16v8 Ah = *(const s16v8*)&hhi[addr];
                s16v8 Al = *(const s16v8*)&hlo[addr];
                MLP_MFMA(acc[rt], Ah, Bh[ks]);
                MLP_MFMA(acc[rt], Ah, Bl[ks]);
                MLP_MFMA(acc[rt], Al, Bh[ks]);
            }
        }
        const float bb = b3[col];
#pragma unroll
        for (int rt = 0; rt < 4; ++rt) {
#pragma unroll
            for (int r = 0; r < 4; ++r) {
                float vv = acc[rt][r] + bb;
                v[rt][r] = vv;
                float s2 = vv * vv;
#pragma unroll
                for (int o = 1; o <= 8; o <<= 1) s2 += __shfl_xor(s2, o);
                if (li == 0) ssw[wl][rt * 16 + g * 4 + r] = s2;
            }
        }
    }
    __syncthreads();                                   // ssw ready
    if (wl < 4) {
        const int col = wl * 16 + li;
        float cs = 0.f;
#pragma unroll
        for (int rt = 0; rt < 4; ++rt) {
#pragma unroll
            for (int r = 0; r < 4; ++r) {
                const int row = rt * 16 + g * 4 + r;
                const float tot = ssw[0][row] + ssw[1][row] +
                                  ssw[2][row] + ssw[3][row];
                const float inv = rsqrtf(tot);
                const int node = n0 + row;
                float ov = v[rt][r] * inv;
                if (node < NN) {
                    out[(size_t)node * 64 + col] = ov;
                    h16out[(size_t)node * 64 + col] = (_Float16)ov;
                    cs += ov;
                }
            }
        }
        cs += __shfl_xor(cs, 16);
        cs += __shfl_xor(cs, 32);
        if (g == 0) colp[col] = cs;
    }
    __syncthreads();                                   // colp ready
    if (t < 64)
        colpart[(size_t)blockIdx.x * 64 + t] = colp[t];
}

// -------------------------------------------------------------------------
extern "C" void kernel_launch(void* const* d_in, const int* in_sizes, int n_in,
                              void* d_out, int out_size, void* d_ws, size_t ws_size,
                              hipStream_t stream) {
    const float* hidden = (const float*)d_in[0];
    const int*   src    = (const int*)d_in[1];
    const int*   dst    = (const int*)d_in[2];
    const float* W1f    = (const float*)d_in[3];
    const float* b1f    = (const float*)d_in[4];
    const float* W2f    = (const float*)d_in[5];
    const float* b2f    = (const float*)d_in[6];
    const float* W3f    = (const float*)d_in[7];
    const float* b3f    = (const float*)d_in[8];

    float* b1e     = (float*)d_ws;                        // 128
    float* partA   = b1e + 128;                           // 256*64 (grep it=0)
    float* partB   = partA + 256 * 64;                    // NBLK*64
    float* hA      = partB + (size_t)NBLK * 64;           // NN*H
    int*   bbase   = (int*)(hA + (size_t)NN * H);         // NB+1
    int*   off     = bbase + (NB + 1);                    // NN+1
    int*   chist   = off + (NN + 1);                      // NCH*NB
    u32*   bin     = (u32*)(chist + NCH * NB);            // NE
    u32*   csr2    = bin + NE;                            // NE (u32)
    u16*   wt      = (u16*)(((uintptr_t)(csr2 + NE) + 255) & ~(uintptr_t)255);
    _Float16* h16a = (_Float16*)(wt + 2 * 81920);         // NN*H fp16
    _Float16* h16b = h16a + (size_t)NN * H;               // NN*H fp16

    // ---- one-time per call: bucketized CSR + weight planes ----
    hist_kernel<<<NCH, 256, 0, stream>>>(dst, chist);
    cscan_kernel<<<1, 512, 0, stream>>>(chist, bbase);
    scat_kernel<<<NCH, 256, 0, stream>>>(src, dst, chist, bin);
    binB_kernel<<<NB, 256, 0, stream>>>(bin, bbase, off, csr2);
    prep_kernel<<<(2 * 40960 + 255) / 256, 256, 0, stream>>>(W1f, W2f, W3f, wt);

    // it=0 grep of the input hidden (fills partA + h16a)
    grep_kernel<<<256, 256, 0, stream>>>(hidden, partA, h16a);

    const float* hin = hidden;
    float* houts[4] = { hA, (float*)d_out, hA, (float*)d_out };
    _Float16* h16bufs[2] = { h16a, h16b };

    for (int it = 0; it < 4; ++it) {
        const int blk = it >> 1;
        const float* part = (it == 0) ? partA : partB;
        const int nparts  = (it == 0) ? 256 : NBLK;
        b1e_kernel<<<1, 1024, 0, stream>>>(part, nparts,
            W1f + blk * 24576, b1f + blk * 128, b1e);
        fused_mlp<<<NBLK, 512, 0, stream>>>(
            h16bufs[it & 1], hin, b1e,
            wt + blk * 81920, b2f + blk * 128, b3f + blk * 64,
            csr2, off,
            houts[it], h16bufs[(it + 1) & 1], partB);
        hin = houts[it];
    }
}

// Round 18
// 409.191 us; speedup vs baseline: 1.8559x; 1.8559x over previous
//
#include <hip/hip_runtime.h>
#include <math.h>

#define NN 50000
#define NE 1600000
#define H  64

#define SHIFT 7                 // 128 nodes per bucket
#define NPBKT 128
#define NB    391               // ceil(50000/128)
#define CHUNK 4096
#define NCH   391               // ceil(NE/CHUNK)

typedef __attribute__((ext_vector_type(8))) short s16v8;   // 8 bf16
typedef __attribute__((ext_vector_type(4))) float f32v4;   // MFMA acc
typedef __attribute__((ext_vector_type(8))) _Float16 f16v8;
typedef unsigned short u16;
typedef unsigned int   u32;

__device__ __forceinline__ u16 f2bf(float x) {             // RNE f32->bf16
    union { float f; unsigned u; } v; v.f = x;
    unsigned r = v.u + 0x7FFF + ((v.u >> 16) & 1);
    return (u16)(r >> 16);
}
__device__ __forceinline__ float bf2f(u16 h) {
    union { float f; unsigned u; } v; v.u = ((unsigned)h) << 16; return v.f;
}

// ============ CSR build, bucketized ============
__global__ __launch_bounds__(256) void hist_kernel(const int* __restrict__ dst,
                                                   int* __restrict__ chunkhist) {
    __shared__ int h[NB];
    const int c = blockIdx.x;
    for (int b = threadIdx.x; b < NB; b += 256) h[b] = 0;
    __syncthreads();
    const int e0 = c * CHUNK, e1 = min(NE, e0 + CHUNK);
    for (int e = e0 + threadIdx.x; e < e1; e += 256)
        atomicAdd(&h[dst[e] >> SHIFT], 1);
    __syncthreads();
    for (int b = threadIdx.x; b < NB; b += 256)
        chunkhist[c * NB + b] = h[b];
}

__global__ __launch_bounds__(512) void cscan_kernel(int* __restrict__ chunkhist,
                                                    int* __restrict__ bbase) {
    __shared__ int s[512];
    const int t = threadIdx.x;
    int tot = 0;
    if (t < NB)
        for (int c = 0; c < NCH; ++c) tot += chunkhist[c * NB + t];
    s[t] = (t < NB) ? tot : 0;
    __syncthreads();
    for (int d = 1; d < 512; d <<= 1) {
        int v = (t >= d) ? s[t - d] : 0;
        __syncthreads();
        s[t] += v;
        __syncthreads();
    }
    if (t < NB) {
        int base = s[t] - tot;             // exclusive
        bbase[t] = base;
        if (t == NB - 1) bbase[NB] = s[t];
        int run = base;
        for (int c = 0; c < NCH; ++c) {
            int tmp = chunkhist[c * NB + t];
            chunkhist[c * NB + t] = run;
            run += tmp;
        }
    }
}

__global__ __launch_bounds__(256) void scat_kernel(const int* __restrict__ src,
                                                   const int* __restrict__ dst,
                                                   const int* __restrict__ chunkhist,
                                                   u32* __restrict__ bin) {
    __shared__ int base[NB];
    __shared__ int cur[NB];
    const int c = blockIdx.x;
    for (int b = threadIdx.x; b < NB; b += 256) {
        base[b] = chunkhist[c * NB + b];
        cur[b] = 0;
    }
    __syncthreads();
    const int e0 = c * CHUNK, e1 = min(NE, e0 + CHUNK);
    for (int e = e0 + threadIdx.x; e < e1; e += 256) {
        int d = dst[e];
        int b = d >> SHIFT;
        int p = atomicAdd(&cur[b], 1);
        bin[base[b] + p] = (u32)src[e] | ((u32)(d & (NPBKT - 1)) << 16);
    }
}

__global__ __launch_bounds__(256) void binB_kernel(const u32* __restrict__ bin,
                                                   const int* __restrict__ bbase,
                                                   int* __restrict__ off,
                                                   u16* __restrict__ csr) {
    __shared__ int deg[NPBKT];
    __shared__ int sc[NPBKT];
    __shared__ int cur[NPBKT];
    const int b = blockIdx.x, t = threadIdx.x;
    const int seg0 = bbase[b], seg1 = bbase[b + 1];
    if (t < NPBKT) { deg[t] = 0; cur[t] = 0; }
    __syncthreads();
    for (int i = seg0 + t; i < seg1; i += 256)
        atomicAdd(&deg[(bin[i] >> 16) & (NPBKT - 1)], 1);
    __syncthreads();
    if (t < NPBKT) sc[t] = deg[t];
    __syncthreads();
    for (int d = 1; d < NPBKT; d <<= 1) {
        int v = 0;
        if (t < NPBKT && t >= d) v = sc[t - d];
        __syncthreads();
        if (t < NPBKT) sc[t] += v;
        __syncthreads();
    }
    if (t < NPBKT) {
        sc[t] -= deg[t];
        int node = b * NPBKT + t;
        if (node < NN) off[node] = seg0 + sc[t];
        if (b == 0 && t == 0) off[NN] = NE;
    }
    __syncthreads();
    for (int i = seg0 + t; i < seg1; i += 256) {
        u32 e = bin[i];
        int n = (e >> 16) & (NPBKT - 1);
        int p = atomicAdd(&cur[n], 1);
        csr[seg0 + sc[n] + p] = (u16)(e & 0xFFFF);
    }
}

// ============ weight prep: transpose + split into bf16 hi/lo planes ======
__global__ __launch_bounds__(256) void prep_kernel(const float* __restrict__ W1,
        const float* __restrict__ W2, const float* __restrict__ W3,
        u16* __restrict__ wt) {
    int idx = blockIdx.x * 256 + threadIdx.x;
    if (idx >= 2 * 40960) return;
    int b = idx / 40960, r = idx - b * 40960;
    float v; int hioff, losz;
    if (r < 16384) {
        int col = r >> 7, k = r & 127;
        v = W1[b * 24576 + k * 128 + col];
        hioff = b * 81920 + r; losz = 16384;
    } else if (r < 32768) {
        int rr = r - 16384; int col = rr >> 7, k = rr & 127;
        v = W2[b * 16384 + k * 128 + col];
        hioff = b * 81920 + 32768 + rr; losz = 16384;
    } else {
        int rr = r - 32768; int col = rr >> 7, k = rr & 127;
        v = W3[b * 8192 + k * 64 + col];
        hioff = b * 81920 + 65536 + rr; losz = 8192;
    }
    u16 hi = f2bf(v);
    u16 lo = f2bf(v - bf2f(hi));
    wt[hioff] = hi; wt[hioff + losz] = lo;
}

// ============ grep partials + fp16 copy (it=0 only) ============
__global__ __launch_bounds__(256) void grep_kernel(const float* __restrict__ h,
                                                   float* __restrict__ partial,
                                                   _Float16* __restrict__ h16) {
    const int c  = threadIdx.x & 63;
    const int rl = threadIdx.x >> 6;
    float acc = 0.f;
    for (int r = blockIdx.x * 4 + rl; r < NN; r += gridDim.x * 4) {
        float v = h[r * H + c];
        h16[r * H + c] = (_Float16)v;
        acc += v;
    }
    __shared__ float s[4][64];
    s[rl][c] = acc;
    __syncthreads();
    if (threadIdx.x < 64)
        partial[blockIdx.x * 64 + threadIdx.x] =
            s[0][threadIdx.x] + s[1][threadIdx.x] +
            s[2][threadIdx.x] + s[3][threadIdx.x];
}

// ============ b1e: 1024-thread reduce + fold grep into layer-1 bias ======
__global__ __launch_bounds__(1024) void b1e_kernel(const float* __restrict__ partial,
        int nparts,
        const float* __restrict__ W1, const float* __restrict__ b1,
        float* __restrict__ b1e) {
    __shared__ float sg[16][64];
    __shared__ float g[64];
    const int t = threadIdx.x;
    const int c = t & 63, rl = t >> 6;           // rl in [0,16)
    float s = 0.f;
    for (int i = rl; i < nparts; i += 16) s += partial[i * 64 + c];
    sg[rl][c] = s;
    __syncthreads();
    if (t < 64) {
        float a = 0.f;
#pragma unroll
        for (int j = 0; j < 16; ++j) a += sg[j][t];
        g[t] = a;
    }
    __syncthreads();
    if (t < 128) {
        float s2 = b1[t];
        for (int k = 0; k < 64; ++k)
            s2 = fmaf(g[k], W1[(128 + k) * 128 + t], s2);
        b1e[t] = s2;
    }
}

// ============ FUSED gather + MFMA MLP (R9 single-plane body) ============
// 64 nodes/block, 8 waves. Gather prologue: wave wl -> nodes n0+wl*8..+7,
// 8 lanes/node (lane covers 8 dims via f16v8), independent per-lane chains,
// result written as bf16 hi/lo directly into swizzled x-plane cols 0-63.
// hin staged into cols 64-127. Then R9's proven single-plane MLP:
// L1/L2 all 8 waves (col-tile wl), L3 waves 0-3, fused h16/colpart epilogue.
#define MLP_MFMA(d, a, b) d = __builtin_amdgcn_mfma_f32_16x16x32_bf16(a, b, d, 0, 0, 0)

__global__ __launch_bounds__(512, 4) void fused_mlp(
    const _Float16* __restrict__ h16in, const float* __restrict__ hin,
    const float* __restrict__ b1e, const u16* __restrict__ wt,
    const float* __restrict__ b2, const float* __restrict__ b3,
    const u16* __restrict__ csr, const int* __restrict__ off,
    float* __restrict__ out, _Float16* __restrict__ h16out,
    float* __restrict__ colpart)
{
    __shared__ u16 hhi[64 * 128], hlo[64 * 128];
    __shared__ float ssw[4][64];
    __shared__ float colp[64];
    const int t = threadIdx.x;
    const int wl = t >> 6, lane = t & 63;
    const int li = lane & 15, g = lane >> 4;
    const int n0 = blockIdx.x * 64;

    const u16* w1hi = wt;
    const u16* w1lo = wt + 16384;
    const u16* w2hi = wt + 32768;
    const u16* w2lo = wt + 49152;
    const u16* w3hi = wt + 65536;
    const u16* w3lo = wt + 73728;

    // ---- gather: agg half of x (cols 0-63) ----
    {
        const int nl = lane >> 3, sub = lane & 7;
        const int node = min(n0 + wl * 8 + nl, NN - 1);
        const int beg = off[node], end = off[node + 1];
        float a[8] = {0.f, 0.f, 0.f, 0.f, 0.f, 0.f, 0.f, 0.f};
        int e = beg;
        for (; e + 1 < end; e += 2) {              // two chains in flight
            const int s0 = csr[e], s1 = csr[e + 1];
            f16v8 v0 = *(const f16v8*)&h16in[(size_t)s0 * 64 + sub * 8];
            f16v8 v1 = *(const f16v8*)&h16in[(size_t)s1 * 64 + sub * 8];
#pragma unroll
            for (int j = 0; j < 8; ++j) a[j] += (float)v0[j] + (float)v1[j];
        }
        if (e < end) {
            const int s0 = csr[e];
            f16v8 v0 = *(const f16v8*)&h16in[(size_t)s0 * 64 + sub * 8];
#pragma unroll
            for (int j = 0; j < 8; ++j) a[j] += (float)v0[j];
        }
        const int row = wl * 8 + nl;
        s16v8 hv, lv;
#pragma unroll
        for (int j = 0; j < 8; ++j) {
            u16 hb = f2bf(a[j]);
            hv[j] = (short)hb;
            lv[j] = (short)f2bf(a[j] - bf2f(hb));
        }
        const int addr = row * 128 + ((sub ^ (row & 7)) << 3);
        *(s16v8*)&hhi[addr] = hv;
        *(s16v8*)&hlo[addr] = lv;
    }
    // ---- stage hin half of x (cols 64-127) ----
    {
        const int row = t >> 3, c8 = t & 7;
        const int node = min(n0 + row, NN - 1);
        const float* sp = hin + (size_t)node * 64 + c8 * 8;
        float4 u0 = *(const float4*)sp;
        float4 u1 = *(const float4*)(sp + 4);
        float f[8] = {u0.x, u0.y, u0.z, u0.w, u1.x, u1.y, u1.z, u1.w};
        s16v8 hv, lv;
#pragma unroll
        for (int j = 0; j < 8; ++j) {
            u16 hb = f2bf(f[j]);
            hv[j] = (short)hb;
            lv[j] = (short)f2bf(f[j] - bf2f(hb));
        }
        const int cb = 8 + c8;
        const int addr = row * 128 + ((cb ^ (row & 7)) << 3);
        *(s16v8*)&hhi[addr] = hv;
        *(s16v8*)&hlo[addr] = lv;
    }
    __syncthreads();                                   // x ready

    // ================= L1 (x -> h1) =================
    {
        const int col = wl * 16 + li;
        s16v8 Bh[4], Bl[4];
#pragma unroll
        for (int ks = 0; ks < 4; ++ks) {
            Bh[ks] = *(const s16v8*)(w1hi + col * 128 + ks * 32 + g * 8);
            Bl[ks] = *(const s16v8*)(w1lo + col * 128 + ks * 32 + g * 8);
        }
        f32v4 acc[4];
#pragma unroll
        for (int i = 0; i < 4; ++i) acc[i] = (f32v4){0.f, 0.f, 0.f, 0.f};
#pragma unroll
        for (int rt = 0; rt < 4; ++rt) {
            const int row = rt * 16 + li;
#pragma unroll
            for (int ks = 0; ks < 4; ++ks) {
                const int kb = ks * 4 + g;
                const int addr = row * 128 + ((kb ^ (row & 7)) << 3);
                s16v8 Ah = *(const s16v8*)&hhi[addr];
                s16v8 Al = *(const s16v8*)&hlo[addr];
                MLP_MFMA(acc[rt], Ah, Bh[ks]);
                MLP_MFMA(acc[rt], Ah, Bl[ks]);
                MLP_MFMA(acc[rt], Al, Bh[ks]);
            }
        }
        __syncthreads();                        // all x reads complete
        const float bb = b1e[col];
        const int cb = col >> 3, c7 = col & 7;
#pragma unroll
        for (int rt = 0; rt < 4; ++rt) {
#pragma unroll
            for (int r = 0; r < 4; ++r) {
                float hv = fmaxf(acc[rt][r] + bb, 0.f);
                u16 hb = f2bf(hv);
                u16 lb = f2bf(hv - bf2f(hb));
                const int row = rt * 16 + g * 4 + r;
                const int addr = row * 128 + (((cb ^ (row & 7)) << 3) | c7);
                hhi[addr] = hb; hlo[addr] = lb;
            }
        }
    }
    __syncthreads();                                   // h1 ready

    // ================= L2 (h1 -> h2) =================
    {
        const int col = wl * 16 + li;
        s16v8 Bh[4], Bl[4];
#pragma unroll
        for (int ks = 0; ks < 4; ++ks) {
            Bh[ks] = *(const s16v8*)(w2hi + col * 128 + ks * 32 + g * 8);
            Bl[ks] = *(const s16v8*)(w2lo + col * 128 + ks * 32 + g * 8);
        }
        f32v4 acc[4];
#pragma unroll
        for (int i = 0; i < 4; ++i) acc[i] = (f32v4){0.f, 0.f, 0.f, 0.f};
#pragma unroll
        for (int rt = 0; rt < 4; ++rt) {
            const int row = rt * 16 + li;
#pragma unroll
            for (int ks = 0; ks < 4; ++ks) {
                const int kb = ks * 4 + g;
                const int addr = row * 128 + ((kb ^ (row & 7)) << 3);
                s16v8 Ah = *(const s16v8*)&hhi[addr];
                s16v8 Al = *(const s16v8*)&hlo[addr];
                MLP_MFMA(acc[rt], Ah, Bh[ks]);
                MLP_MFMA(acc[rt], Ah, Bl[ks]);
                MLP_MFMA(acc[rt], Al, Bh[ks]);
            }
        }
        __syncthreads();                        // all h1 reads complete
        const float bb = b2[col];
        const int cb = col >> 3, c7 = col & 7;
#pragma unroll
        for (int rt = 0; rt < 4; ++rt) {
#pragma unroll
            for (int r = 0; r < 4; ++r) {
                float hv = fmaxf(acc[rt][r] + bb, 0.f);
                u16 hb = f2bf(hv);
                u16 lb = f2bf(hv - bf2f(hb));
                const int row = rt * 16 + g * 4 + r;
                const int addr = row * 128 + (((cb ^ (row & 7)) << 3) | c7);
                hhi[addr] = hb; hlo[addr] = lb;
            }
        }
    }
    __syncthreads();                                   // h2 ready

    // ========== L3 (h2 -> out, waves 0-3) + norm + h16 + colsum ==========
    float v[4][4];
    if (wl < 4) {
        const int col = wl * 16 + li;
        s16v8 Bh[4], Bl[4];
#pragma unroll
        for (int ks = 0; ks < 4; ++ks) {
            Bh[ks] = *(const s16v8*)(w3hi + col * 128 + ks * 32 + g * 8);
            Bl[ks] = *(const s16v8*)(w3lo + col * 128 + ks * 32 + g * 8);
        }
        f32v4 acc[4];
#pragma unroll
        for (int i = 0; i < 4; ++i) acc[i] = (f32v4){0.f, 0.f, 0.f, 0.f};
#pragma unroll
        for (int rt = 0; rt < 4; ++rt) {
            const int row = rt * 16 + li;
#pragma unroll
            for (int ks = 0; ks < 4; ++ks) {
                const int kb = ks * 4 + g;
                const int addr = row * 128 + ((kb ^ (row & 7)) << 3);
                s16v8 Ah = *(const s16v8*)&hhi[addr];
                s16v8 Al = *(const s16v8*)&hlo[addr];
                MLP_MFMA(acc[rt], Ah, Bh[ks]);
                MLP_MFMA(acc[rt], Ah, Bl[ks]);
                MLP_MFMA(acc[rt], Al, Bh[ks]);
            }
        }
        const float bb = b3[col];
#pragma unroll
        for (int rt = 0; rt < 4; ++rt) {
#pragma unroll
            for (int r = 0; r < 4; ++r) {
                float vv = acc[rt][r] + bb;
                v[rt][r] = vv;
                float s2 = vv * vv;
#pragma unroll
                for (int o = 1; o <= 8; o <<= 1) s2 += __shfl_xor(s2, o);
                if (li == 0) ssw[wl][rt * 16 + g * 4 + r] = s2;
            }
        }
    }
    __syncthreads();                                   // ssw ready
    if (wl < 4) {
        const int col = wl * 16 + li;
        float cs = 0.f;
#pragma unroll
        for (int rt = 0; rt < 4; ++rt) {
#pragma unroll
            for (int r = 0; r < 4; ++r) {
                const int row = rt * 16 + g * 4 + r;
                const float tot = ssw[0][row] + ssw[1][row] +
                                  ssw[2][row] + ssw[3][row];
                const float inv = rsqrtf(tot);
                const int node = n0 + row;
                float ov = v[rt][r] * inv;
                if (node < NN) {
                    out[(size_t)node * 64 + col] = ov;
                    h16out[(size_t)node * 64 + col] = (_Float16)ov;
                    cs += ov;
                }
            }
        }
        cs += __shfl_xor(cs, 16);
        cs += __shfl_xor(cs, 32);
        if (g == 0) colp[col] = cs;
    }
    __syncthreads();                                   // colp ready
    if (t < 64)
        colpart[(size_t)blockIdx.x * 64 + t] = colp[t];
}

// -------------------------------------------------------------------------
extern "C" void kernel_launch(void* const* d_in, const int* in_sizes, int n_in,
                              void* d_out, int out_size, void* d_ws, size_t ws_size,
                              hipStream_t stream) {
    const float* hidden = (const float*)d_in[0];
    const int*   src    = (const int*)d_in[1];
    const int*   dst    = (const int*)d_in[2];
    const float* W1f    = (const float*)d_in[3];
    const float* b1f    = (const float*)d_in[4];
    const float* W2f    = (const float*)d_in[5];
    const float* b2f    = (const float*)d_in[6];
    const float* W3f    = (const float*)d_in[7];
    const float* b3f    = (const float*)d_in[8];

    const int NBLK = (NN + 63) / 64;                      // 782

    float* b1e     = (float*)d_ws;                        // 128
    float* partA   = b1e + 128;                           // 256*64 (grep it=0)
    float* partB   = partA + 256 * 64;                    // NBLK*64 (fused)
    float* hA      = partB + (size_t)NBLK * 64;           // NN*H
    int*   bbase   = (int*)(hA + (size_t)NN * H);         // NB+1
    int*   off     = bbase + (NB + 1);                    // NN+1
    int*   chist   = off + (NN + 1);                      // NCH*NB
    u32*   bin     = (u32*)(chist + NCH * NB);            // NE
    u16*   csr     = (u16*)(bin + NE);                    // NE
    u16*   wt      = (u16*)(((uintptr_t)(csr + NE) + 255) & ~(uintptr_t)255);
    _Float16* h16a = (_Float16*)(wt + 2 * 81920);         // NN*H fp16
    _Float16* h16b = h16a + (size_t)NN * H;               // NN*H fp16

    // ---- one-time per call: bucketized CSR + weight planes ----
    hist_kernel<<<NCH, 256, 0, stream>>>(dst, chist);
    cscan_kernel<<<1, 512, 0, stream>>>(chist, bbase);
    scat_kernel<<<NCH, 256, 0, stream>>>(src, dst, chist, bin);
    binB_kernel<<<NB, 256, 0, stream>>>(bin, bbase, off, csr);
    prep_kernel<<<(2 * 40960 + 255) / 256, 256, 0, stream>>>(W1f, W2f, W3f, wt);

    // it=0 grep of the input hidden (fills partA + h16a)
    grep_kernel<<<256, 256, 0, stream>>>(hidden, partA, h16a);

    const float* hin = hidden;
    float* houts[4] = { hA, (float*)d_out, hA, (float*)d_out };
    _Float16* h16bufs[2] = { h16a, h16b };

    for (int it = 0; it < 4; ++it) {
        const int blk = it >> 1;
        const float* part = (it == 0) ? partA : partB;
        const int nparts  = (it == 0) ? 256 : NBLK;
        b1e_kernel<<<1, 1024, 0, stream>>>(part, nparts,
            W1f + blk * 24576, b1f + blk * 128, b1e);
        fused_mlp<<<NBLK, 512, 0, stream>>>(
            h16bufs[it & 1], hin, b1e,
            wt + blk * 81920, b2f + blk * 128, b3f + blk * 64,
            csr, off,
            houts[it], h16bufs[(it + 1) & 1], partB);
        hin = houts[it];
    }
}